// Round 12
// baseline (1943.884 us; speedup 1.0000x reference)
//
#include <hip/hip_runtime.h>
#include <math.h>

#define HN 512   // hidden states
#define HM 4096  // emission symbols
#define HB 64    // batch
#define HT 512   // max seq len

// ---- 4-bit dot path (encoding must match between prep + fwd) ----
#if __has_builtin(__builtin_amdgcn_udot8)
  #define ENC_BIASED 0
  __device__ __forceinline__ int dot8q(unsigned int a, unsigned int b, int c){
    return (int)__builtin_amdgcn_udot8(a, b, (unsigned int)c, false);
  }
#elif __has_builtin(__builtin_amdgcn_sdot8)
  #define ENC_BIASED 1
  __device__ __forceinline__ int dot8q(unsigned int a, unsigned int b, int c){
    return __builtin_amdgcn_sdot8((int)a, (int)b, c, false);
  }
#else
  #define ENC_BIASED 0
  __device__ __forceinline__ int dot4u8f(unsigned int a, unsigned int b, int c){
#if __has_builtin(__builtin_amdgcn_sdot4)
    return __builtin_amdgcn_sdot4((int)a, (int)b, c, false);   // vals<=15, sign-safe
#else
    c += (int)(a & 0xffu)       * (int)(b & 0xffu);
    c += (int)((a>>8) & 0xffu)  * (int)((b>>8) & 0xffu);
    c += (int)((a>>16) & 0xffu) * (int)((b>>16) & 0xffu);
    c += (int)(a>>24)           * (int)(b>>24);
    return c;
#endif
  }
  __device__ __forceinline__ int dot8q(unsigned int a, unsigned int b, int c){
    unsigned int al = a & 0x0F0F0F0Fu, ah = (a>>4) & 0x0F0F0F0Fu;
    unsigned int bl = b & 0x0F0F0F0Fu, bh = (b>>4) & 0x0F0F0F0Fu;
    c = dot4u8f(al, bl, c);
    return dot4u8f(ah, bh, c);
  }
#endif

__device__ __forceinline__ float rcpf(float x){
#if __has_builtin(__builtin_amdgcn_rcpf)
  return __builtin_amdgcn_rcpf(x);
#else
  return 1.0f / x;
#endif
}

__device__ __forceinline__ float wsum(float v){
  #pragma unroll
  for(int o=32;o>0;o>>=1) v += __shfl_xor(v,o,64);
  return v;
}
__device__ __forceinline__ float wmax(float v){
  #pragma unroll
  for(int o=32;o>0;o>>=1) v = fmaxf(v,__shfl_xor(v,o,64));
  return v;
}

__device__ __forceinline__ float blockSum512(float v, float* red, float* bc){
  v = wsum(v);
  if((threadIdx.x & 63)==0) red[threadIdx.x>>6] = v;
  __syncthreads();
  if(threadIdx.x < 64){
    float s = (threadIdx.x<8)? red[threadIdx.x] : 0.0f;
    #pragma unroll
    for(int o=4;o>0;o>>=1) s += __shfl_xor(s,o,64);
    if(threadIdx.x==0) *bc = s;
  }
  __syncthreads();
  return *bc;
}
__device__ __forceinline__ float blockMax512(float v, float* red, float* bc){
  v = wmax(v);
  if((threadIdx.x & 63)==0) red[threadIdx.x>>6] = v;
  __syncthreads();
  if(threadIdx.x < 64){
    float s = (threadIdx.x<8)? red[threadIdx.x] : -INFINITY;
    #pragma unroll
    for(int o=4;o>0;o>>=1) s = fmaxf(s, __shfl_xor(s,o,64));
    if(threadIdx.x==0) *bc = s;
  }
  __syncthreads();
  return *bc;
}

__device__ __forceinline__ unsigned short f2bf(float f){
  unsigned int u = __float_as_uint(f);
  unsigned int r = (u + 0x7fffu + ((u>>16)&1u)) >> 16;  // RNE
  return (unsigned short)r;
}
__device__ __forceinline__ float bf2f(unsigned int w){ return __uint_as_float(w<<16); }

// ---------------- prep kernels ----------------

__global__ __launch_bounds__(512) void k_em_lse(const float* __restrict__ em, float* __restrict__ em_lse){
  __shared__ float red[8]; __shared__ float bc;
  int r = blockIdx.x;
  const float* row = em + (size_t)r*HM;
  float mx = -INFINITY;
  for(int i=threadIdx.x;i<HM;i+=512) mx = fmaxf(mx, row[i]);
  mx = blockMax512(mx, red, &bc);
  float s = 0.f;
  for(int i=threadIdx.x;i<HM;i+=512) s += expf(row[i]-mx);
  s = blockSum512(s, red, &bc);
  if(threadIdx.x==0) em_lse[r] = mx + logf(s);
}

__global__ __launch_bounds__(512) void k_pri(const float* __restrict__ pri, float* __restrict__ P, float* __restrict__ pric){
  __shared__ float red[8]; __shared__ float bc;
  int j = threadIdx.x;
  float v = pri[j];
  float mx = blockMax512(v, red, &bc);
  float w = expf(v-mx);
  float s = blockSum512(w, red, &bc);
  P[j] = w;
  if(j==0) *pric = -logf(s);
}

// emT[m][j] = bf16( exp(log_em[j][m]) ), LDS-tiled transpose
__global__ __launch_bounds__(256) void k_em_tab(const float* __restrict__ em, const float* __restrict__ em_lse,
                                                unsigned short* __restrict__ emT){
  __shared__ unsigned short tile[64][66];
  __shared__ float lsl[64];
  int m0 = blockIdx.x*64, j0 = blockIdx.y*64;
  int tx = threadIdx.x & 63, ty = threadIdx.x >> 6;
  if(threadIdx.x < 64) lsl[threadIdx.x] = em_lse[j0 + threadIdx.x];
  __syncthreads();
  #pragma unroll
  for(int r=0;r<16;r++){
    int jl = ty*16 + r;
    float v = em[(size_t)(j0+jl)*HM + m0 + tx];
    tile[jl][tx] = f2bf(expf(v - lsl[jl]));
  }
  __syncthreads();
  #pragma unroll
  for(int r=0;r<16;r++){
    int ml = ty*16 + r;
    emT[(size_t)(m0+ml)*HN + j0 + tx] = tile[tx][ml];
  }
}

// column stats of transition col-softmax
__global__ __launch_bounds__(512) void k_trcol(const float* __restrict__ tr,
                                               float* __restrict__ cmax, float* __restrict__ csum){
  __shared__ float red[8]; __shared__ float bc;
  int k = blockIdx.x, j = threadIdx.x;
  float v = tr[(size_t)j*HN + k];
  float mx = blockMax512(v, red, &bc);
  float s  = blockSum512(expf(v-mx), red, &bc);
  if(j==0){ cmax[k] = mx; csum[k] = s; }
}

// row pass: Tr[j,k] -> u4 q = round(Tr*15/rowmax). Byte at j*256 + (k>>5)*16 +
// ((k&31)>>1): lo = even k, hi = k+1. rscale[j]=rm/15; rbar[j]=rowsum residual;
// tsumq[j][c] = per-32k-chunk q sum (c = k>>5, 16 per row; sdot bias path).
__global__ __launch_bounds__(512) void k_trrow(const float* __restrict__ tr,
                                               const float* __restrict__ cmax, const float* __restrict__ csum,
                                               unsigned char* __restrict__ TQ4,
                                               float* __restrict__ rscale, float* __restrict__ rbar,
                                               unsigned short* __restrict__ tsumq){
  __shared__ float red[8]; __shared__ float bc;
  int j = blockIdx.x, k = threadIdx.x;
  float v = expf(tr[(size_t)j*HN + k] - cmax[k]) / csum[k];
  float rm = blockMax512(v, red, &bc);
  int q = __float2int_rn(v * (15.0f/rm));          // 0..15
  float rs = blockSum512(v, red, &bc);             // true row sum
  float qs = blockSum512((float)q, red, &bc);      // total q sum
  // per-32-lane-chunk q sum (xor offsets <32 stay inside the 32-group)
  float cq = (float)q;
  #pragma unroll
  for(int o=1;o<32;o<<=1) cq += __shfl_xor(cq,o,64);
  int qn = __shfl_down(q, 1, 64);
  if((k & 1)==0){
#if ENC_BIASED
    unsigned char by = (unsigned char)(((q-8)&0xF) | (((qn-8)&0xF)<<4));
#else
    unsigned char by = (unsigned char)((q&0xF) | ((qn&0xF)<<4));
#endif
    TQ4[(size_t)j*256 + ((k>>5)<<4) + ((k&31)>>1)] = by;
  }
  if((k&31)==0) tsumq[j*16 + (k>>5)] = (unsigned short)(int)cq;
  if(k==0){
    rscale[j] = rm * (1.0f/15.0f);
    rbar[j]   = rs - (rm * (1.0f/15.0f)) * qs;
  }
}

// ---------------- forward recurrence ----------------
// 64 blocks (1/batch), 1024 threads = 16 waves (4/SIMD — round 11 at 2/SIMD left
// ~1200 cyc/step of un-hidden latency on top of the 1540-cyc ds_read_b128 floor).
// Thread t = (state j = (t>>6)*32 + ((t&63)>>1), k-half h = t&1): dots 8 b128 Tr
// chunks (XOR-swizzled, conflict-free per round 11) against the u4 alpha plane;
// half-partials combine via shfl_xor(1) (paired lanes = same j) — no partial
// buffer, no extra barrier. alpha slices = 32 states (16 slices; chunk c <-> slice c
// so per-chunk scaling stays exact). ONE barrier/step, ping-pong planes, stale-S
// normalizer (exact). Tr-quant bias correction: D += abar*rbar[j].
__global__ __launch_bounds__(1024)
void k_fwd(const int* __restrict__ x, const int* __restrict__ Tl,
           const unsigned short* __restrict__ emTu,
           const float* __restrict__ P, const float* __restrict__ pric,
           const float* __restrict__ rscaleG, const float* __restrict__ rbarG,
           const unsigned short* __restrict__ tsumqG,
           const unsigned int* __restrict__ TQd,
           float* __restrict__ out){
  extern __shared__ char smem[];
  uint4*         trS4  = (uint4*)smem;                         // 131072 B
  uint4*         apl4  = (uint4*)(smem + 131072);              // [2][16] uint4 = 512 B
  unsigned char* aplB  = (unsigned char*)(smem + 131072);
  float*         sigS  = (float*)(smem + 131584);              // [2][16]
  float*         sumS  = (float*)(smem + 131712);              // [2][16]
  float*         aqS   = (float*)(smem + 131840);              // [2][16]
  float*         rawS  = (float*)(smem + 131968);              // [16]
  int*           xls   = (int*)(smem + 132032);                // 2048
  float*         rscL  = (float*)(smem + 134080);              // 2048
  float*         rbarL = (float*)(smem + 136128);              // 2048
  unsigned short* tsumL= (unsigned short*)(smem + 138176);     // 16384
  // total 154560 B

  const int t = threadIdx.x, b = blockIdx.x, w = t>>6, L = t&63;
  const int j = w*32 + (L>>1);          // state
  const int h = L&1;                    // k-half
  const int swz = t&7;

  // ---- stage: swizzled Tr + tables ----
  for(int d=t; d<8192; d+=1024){
    int jj = d>>4, c = d&15, v = 2*jj + (c>>3), ch = c&7;
    trS4[v*8 + (ch ^ (v&7))] = ((const uint4*)TQd)[d];
  }
  if(t < HT) xls[t] = x[b*HT + t];
  if(t < HN){ rscL[t] = rscaleG[t]; rbarL[t] = rbarG[t]; }
  for(int d=t; d<4096; d+=1024) ((unsigned int*)tsumL)[d] = ((const unsigned int*)tsumqG)[d];
  int Tb = Tl[b];
  __syncthreads();

  // ---- init (t = 0) ----
  int m = xls[0];
  float e0 = bf2f((unsigned)emTu[(size_t)m*HN + j]);
  float nvr = e0 * P[j];
  {
    float s = wsum(nvr) * 0.5f;          // states duplicated x2 in wave
    if(L==0) rawS[w] = s;
  }
  __syncthreads();
  float S0;
  {
    float4 g0 = ((float4*)rawS)[0], g1 = ((float4*)rawS)[1];
    float4 g2 = ((float4*)rawS)[2], g3 = ((float4*)rawS)[3];
    S0 = ((g0.x+g0.y)+(g0.z+g0.w))+((g1.x+g1.y)+(g1.z+g1.w))
       + ((g2.x+g2.y)+(g2.z+g2.w))+((g3.x+g3.y)+(g3.z+g3.w));
  }
  float c_acc = pric[0] + __logf(S0);
  float nvd = nvr * rcpf(S0);
  // quantize + stats into buffer 1 (read at tt=1)
  {
    float Mw = fmaxf(wmax(nvd), 1e-30f);
    float sig = Mw * (1.0f/15.0f);
    int aq = __float2int_rn(nvd * (15.0f * rcpf(Mw)));
    float Sw = wsum(nvd) * 0.5f;
#if ENC_BIASED
    float AqSw = wsum((float)aq) * 0.5f;
#endif
    int aqn = __shfl_xor(aq, 2, 64);     // state j+1 (h=0 lane)
    if((L&3)==0)
#if ENC_BIASED
      aplB[256 + w*16 + (L>>2)] = (unsigned char)(((aq-8)&0xF) | (((aqn-8)&0xF)<<4));
#else
      aplB[256 + w*16 + (L>>2)] = (unsigned char)((aq&0xF) | ((aqn&0xF)<<4));
#endif
    if(L==0){
      sigS[16+w] = sig; sumS[16+w] = Sw;
#if ENC_BIASED
      aqS[16+w] = AqSw;
#endif
    }
  }
  int mn = xls[(Tb>1)?1:0];
  float eC = bf2f((unsigned)emTu[(size_t)mn*HN + j]);
  const float rsc = rscL[j], rbr = rbarL[j];

  for(int tt=1; tt<Tb; tt++){
    __syncthreads();                      // the ONE barrier per step
    const int rb = (tt & 1), wb = rb ^ 1;

    // [a] dot over this thread's 8 chunks (global chunk cg = 8h + ch)
    int acc[8];
    #pragma unroll
    for(int i=0;i<8;i++) acc[i] = 0;
    const uint4* aplR = apl4 + 16*rb + 8*h;
    const uint4* trR  = trS4 + t*8;
    #pragma unroll
    for(int ch=0; ch<8; ch++){
      uint4 T = trR[ch ^ swz];
      uint4 A = aplR[ch ^ swz];
      int ci = ch ^ swz;
      acc[ci] = dot8q(T.x, A.x, acc[ci]);
      acc[ci] = dot8q(T.y, A.y, acc[ci]);
      acc[ci] = dot8q(T.z, A.z, acc[ci]);
      acc[ci] = dot8q(T.w, A.w, acc[ci]);
    }

    // [b] previous-step stats (uniform-ish reads)
    float4 g0 = ((float4*)(sumS + 16*rb))[0], g1 = ((float4*)(sumS + 16*rb))[1];
    float4 g2 = ((float4*)(sumS + 16*rb))[2], g3 = ((float4*)(sumS + 16*rb))[3];
    float Sp = ((g0.x+g0.y)+(g0.z+g0.w))+((g1.x+g1.y)+(g1.z+g1.w))
             + ((g2.x+g2.y)+(g2.z+g2.w))+((g3.x+g3.y)+(g3.z+g3.w));
    if(tt > 1) c_acc += __logf(Sp);
    float d_inv = rcpf(Sp);
    float abar  = Sp * (1.0f/512.0f);
    float4 s0 = ((float4*)(sigS + 16*rb + 8*h))[0], s1 = ((float4*)(sigS + 16*rb + 8*h))[1];
    float sg[8] = {s0.x,s0.y,s0.z,s0.w,s1.x,s1.y,s1.z,s1.w};

    // [c] combine with per-slice scales (+ sdot bias correction)
    float Af = 0.f;
#if ENC_BIASED
    {
      float4 a0 = ((float4*)(aqS + 16*rb + 8*h))[0], a1 = ((float4*)(aqS + 16*rb + 8*h))[1];
      float av[8] = {a0.x,a0.y,a0.z,a0.w,a1.x,a1.y,a1.z,a1.w};
      uint4 tq = *(const uint4*)(tsumL + j*16 + 8*h);
      int ts[8] = {(int)(tq.x&0xffff),(int)(tq.x>>16),(int)(tq.y&0xffff),(int)(tq.y>>16),
                   (int)(tq.z&0xffff),(int)(tq.z>>16),(int)(tq.w&0xffff),(int)(tq.w>>16)};
      #pragma unroll
      for(int i=0;i<8;i++)
        Af += sg[i] * (float)(acc[i] + 8*(ts[i] + (int)av[i]) - 2048);
    }
#else
    #pragma unroll
    for(int i=0;i<8;i++) Af += sg[i] * (float)acc[i];
#endif
    Af += __shfl_xor(Af, 1, 64);          // combine k-halves (paired lanes, same j)
    float D = rsc * Af + abar * rbr;
    nvd = fmaxf(D * eC * d_inv, 0.0f);

    // prefetch next emission
    int tn = (tt+1 < HT)? tt+1 : HT-1;
    mn = xls[tn];
    float eN = bf2f((unsigned)emTu[(size_t)mn*HN + j]);

    // [e] wave-local finalize (32 states, duplicated x2)
    float Mw = fmaxf(wmax(nvd), 1e-30f);
    float sig = Mw * (1.0f/15.0f);
    int aq = __float2int_rn(nvd * (15.0f * rcpf(Mw)));
    float Sw = wsum(nvd) * 0.5f;
#if ENC_BIASED
    float AqSw = wsum((float)aq) * 0.5f;
#endif
    int aqn = __shfl_xor(aq, 2, 64);
    if((L&3)==0)
#if ENC_BIASED
      aplB[256*wb + w*16 + (L>>2)] = (unsigned char)(((aq-8)&0xF) | (((aqn-8)&0xF)<<4));
#else
      aplB[256*wb + w*16 + (L>>2)] = (unsigned char)((aq&0xF) | ((aqn&0xF)<<4));
#endif
    if(L==0){
      sigS[16*wb+w] = sig; sumS[16*wb+w] = Sw;
#if ENC_BIASED
      aqS[16*wb+w] = AqSw;
#endif
    }
    eC = eN;
  }

  // ---- flush last step's S ----
  __syncthreads();
  {
    const int fb = (Tb & 1);
    float4 g0 = ((float4*)(sumS + 16*fb))[0], g1 = ((float4*)(sumS + 16*fb))[1];
    float4 g2 = ((float4*)(sumS + 16*fb))[2], g3 = ((float4*)(sumS + 16*fb))[3];
    float Sf = ((g0.x+g0.y)+(g0.z+g0.w))+((g1.x+g1.y)+(g1.z+g1.w))
             + ((g2.x+g2.y)+(g2.z+g2.w))+((g3.x+g3.y)+(g3.z+g3.w));
    if(t==0) out[b] = c_acc + __logf(Sf);
  }
}

extern "C" void kernel_launch(void* const* d_in, const int* in_sizes, int n_in,
                              void* d_out, int out_size, void* d_ws, size_t ws_size,
                              hipStream_t stream){
  const int*   x   = (const int*)d_in[0];
  const int*   T   = (const int*)d_in[1];
  const float* em  = (const float*)d_in[2];
  const float* tr  = (const float*)d_in[3];
  const float* pri = (const float*)d_in[4];
  float* out = (float*)d_out;

  char* ws = (char*)d_ws;
  float* em_lse = (float*)ws;                                   // 2 KiB
  float* P      = (float*)(ws + 2048);                          // 2 KiB
  float* pric   = (float*)(ws + 4096);                          // 16 B
  float* cmax   = (float*)(ws + 8192);                          // 2 KiB
  float* csum   = (float*)(ws + 10240);                         // 2 KiB
  float* rscale = (float*)(ws + 12288);                         // 2 KiB
  float* rbar   = (float*)(ws + 14336);                         // 2 KiB
  unsigned short* tsumq = (unsigned short*)(ws + 16384);        // 16 KiB
  unsigned short* emT = (unsigned short*)(ws + 32768);          // 4 MiB
  unsigned char*  TQ4 = (unsigned char*)(ws + 32768 + (size_t)HM*HN*2);  // 128 KiB

  k_em_lse<<<HN, 512, 0, stream>>>(em, em_lse);
  k_pri   <<<1,  512, 0, stream>>>(pri, P, pric);
  k_trcol <<<HN, 512, 0, stream>>>(tr, cmax, csum);
  k_trrow <<<HN, 512, 0, stream>>>(tr, cmax, csum, TQ4, rscale, rbar, tsumq);
  k_em_tab<<<dim3(HM/64, HN/64), 256, 0, stream>>>(em, em_lse, emT);

  const int lds_bytes = 154560;
  (void)hipFuncSetAttribute((const void*)k_fwd, hipFuncAttributeMaxDynamicSharedMemorySize, lds_bytes);
  k_fwd<<<HB, 1024, lds_bytes, stream>>>(x, T, emT, P, pric, rscale, rbar, tsumq,
                                         (const unsigned int*)TQ4, out);
}

// Round 13
// 578.264 us; speedup vs baseline: 3.3616x; 3.3616x over previous
//
#include <hip/hip_runtime.h>
#include <math.h>

#define HN 512   // hidden states
#define HM 4096  // emission symbols
#define HB 64    // batch
#define HT 512   // max seq len

// ---- 4-bit dot path (encoding must match between prep + fwd) ----
#if __has_builtin(__builtin_amdgcn_udot8)
  #define ENC_BIASED 0
  __device__ __forceinline__ int dot8q(unsigned int a, unsigned int b, int c){
    return (int)__builtin_amdgcn_udot8(a, b, (unsigned int)c, false);
  }
#elif __has_builtin(__builtin_amdgcn_sdot8)
  #define ENC_BIASED 1
  __device__ __forceinline__ int dot8q(unsigned int a, unsigned int b, int c){
    return __builtin_amdgcn_sdot8((int)a, (int)b, c, false);
  }
#else
  #define ENC_BIASED 0
  __device__ __forceinline__ int dot4u8f(unsigned int a, unsigned int b, int c){
#if __has_builtin(__builtin_amdgcn_sdot4)
    return __builtin_amdgcn_sdot4((int)a, (int)b, c, false);   // vals<=15, sign-safe
#else
    c += (int)(a & 0xffu)       * (int)(b & 0xffu);
    c += (int)((a>>8) & 0xffu)  * (int)((b>>8) & 0xffu);
    c += (int)((a>>16) & 0xffu) * (int)((b>>16) & 0xffu);
    c += (int)(a>>24)           * (int)(b>>24);
    return c;
#endif
  }
  __device__ __forceinline__ int dot8q(unsigned int a, unsigned int b, int c){
    unsigned int al = a & 0x0F0F0F0Fu, ah = (a>>4) & 0x0F0F0F0Fu;
    unsigned int bl = b & 0x0F0F0F0Fu, bh = (b>>4) & 0x0F0F0F0Fu;
    c = dot4u8f(al, bl, c);
    return dot4u8f(ah, bh, c);
  }
#endif

__device__ __forceinline__ float rcpf(float x){
#if __has_builtin(__builtin_amdgcn_rcpf)
  return __builtin_amdgcn_rcpf(x);
#else
  return 1.0f / x;
#endif
}

__device__ __forceinline__ float wsum(float v){
  #pragma unroll
  for(int o=32;o>0;o>>=1) v += __shfl_xor(v,o,64);
  return v;
}
__device__ __forceinline__ float wmax(float v){
  #pragma unroll
  for(int o=32;o>0;o>>=1) v = fmaxf(v,__shfl_xor(v,o,64));
  return v;
}

__device__ __forceinline__ float blockSum512(float v, float* red, float* bc){
  v = wsum(v);
  if((threadIdx.x & 63)==0) red[threadIdx.x>>6] = v;
  __syncthreads();
  if(threadIdx.x < 64){
    float s = (threadIdx.x<8)? red[threadIdx.x] : 0.0f;
    #pragma unroll
    for(int o=4;o>0;o>>=1) s += __shfl_xor(s,o,64);
    if(threadIdx.x==0) *bc = s;
  }
  __syncthreads();
  return *bc;
}
__device__ __forceinline__ float blockMax512(float v, float* red, float* bc){
  v = wmax(v);
  if((threadIdx.x & 63)==0) red[threadIdx.x>>6] = v;
  __syncthreads();
  if(threadIdx.x < 64){
    float s = (threadIdx.x<8)? red[threadIdx.x] : -INFINITY;
    #pragma unroll
    for(int o=4;o>0;o>>=1) s = fmaxf(s, __shfl_xor(s,o,64));
    if(threadIdx.x==0) *bc = s;
  }
  __syncthreads();
  return *bc;
}

__device__ __forceinline__ unsigned short f2bf(float f){
  unsigned int u = __float_as_uint(f);
  unsigned int r = (u + 0x7fffu + ((u>>16)&1u)) >> 16;  // RNE
  return (unsigned short)r;
}
__device__ __forceinline__ float bf2f(unsigned int w){ return __uint_as_float(w<<16); }

// ---------------- prep kernels ----------------

__global__ __launch_bounds__(512) void k_em_lse(const float* __restrict__ em, float* __restrict__ em_lse){
  __shared__ float red[8]; __shared__ float bc;
  int r = blockIdx.x;
  const float* row = em + (size_t)r*HM;
  float mx = -INFINITY;
  for(int i=threadIdx.x;i<HM;i+=512) mx = fmaxf(mx, row[i]);
  mx = blockMax512(mx, red, &bc);
  float s = 0.f;
  for(int i=threadIdx.x;i<HM;i+=512) s += expf(row[i]-mx);
  s = blockSum512(s, red, &bc);
  if(threadIdx.x==0) em_lse[r] = mx + logf(s);
}

__global__ __launch_bounds__(512) void k_pri(const float* __restrict__ pri, float* __restrict__ P, float* __restrict__ pric){
  __shared__ float red[8]; __shared__ float bc;
  int j = threadIdx.x;
  float v = pri[j];
  float mx = blockMax512(v, red, &bc);
  float w = expf(v-mx);
  float s = blockSum512(w, red, &bc);
  P[j] = w;
  if(j==0) *pric = -logf(s);
}

// emT[m][j] = bf16( exp(log_em[j][m]) ), LDS-tiled transpose
__global__ __launch_bounds__(256) void k_em_tab(const float* __restrict__ em, const float* __restrict__ em_lse,
                                                unsigned short* __restrict__ emT){
  __shared__ unsigned short tile[64][66];
  __shared__ float lsl[64];
  int m0 = blockIdx.x*64, j0 = blockIdx.y*64;
  int tx = threadIdx.x & 63, ty = threadIdx.x >> 6;
  if(threadIdx.x < 64) lsl[threadIdx.x] = em_lse[j0 + threadIdx.x];
  __syncthreads();
  #pragma unroll
  for(int r=0;r<16;r++){
    int jl = ty*16 + r;
    float v = em[(size_t)(j0+jl)*HM + m0 + tx];
    tile[jl][tx] = f2bf(expf(v - lsl[jl]));
  }
  __syncthreads();
  #pragma unroll
  for(int r=0;r<16;r++){
    int ml = ty*16 + r;
    emT[(size_t)(m0+ml)*HN + j0 + tx] = tile[tx][ml];
  }
}

// column stats of transition col-softmax
__global__ __launch_bounds__(512) void k_trcol(const float* __restrict__ tr,
                                               float* __restrict__ cmax, float* __restrict__ csum){
  __shared__ float red[8]; __shared__ float bc;
  int k = blockIdx.x, j = threadIdx.x;
  float v = tr[(size_t)j*HN + k];
  float mx = blockMax512(v, red, &bc);
  float s  = blockSum512(expf(v-mx), red, &bc);
  if(j==0){ cmax[k] = mx; csum[k] = s; }
}

// row pass: Tr[j,k] -> u4 q = round(Tr*15/rowmax). Byte at j*256 + (k>>5)*16 +
// ((k&31)>>1): lo = even k, hi = k+1 (matches alpha packing).
// rscale[j]=rm/15; rbar[j]=rowsum residual; tsumq[j][w] = per-64k-slice q sum.
__global__ __launch_bounds__(512) void k_trrow(const float* __restrict__ tr,
                                               const float* __restrict__ cmax, const float* __restrict__ csum,
                                               unsigned char* __restrict__ TQ4,
                                               float* __restrict__ rscale, float* __restrict__ rbar,
                                               unsigned short* __restrict__ tsumq){
  __shared__ float red[8]; __shared__ float bc;
  int j = blockIdx.x, k = threadIdx.x;
  float v = expf(tr[(size_t)j*HN + k] - cmax[k]) / csum[k];
  float rm = blockMax512(v, red, &bc);
  int q = __float2int_rn(v * (15.0f/rm));          // 0..15
  float rs = blockSum512(v, red, &bc);             // true row sum
  float qs = blockSum512((float)q, red, &bc);      // total q sum
  float wq = wsum((float)q);                       // per-wave(64k) q sum
  int qn = __shfl_down(q, 1, 64);
  if((k & 1)==0){
#if ENC_BIASED
    unsigned char by = (unsigned char)(((q-8)&0xF) | (((qn-8)&0xF)<<4));
#else
    unsigned char by = (unsigned char)((q&0xF) | ((qn&0xF)<<4));
#endif
    TQ4[(size_t)j*256 + ((k>>5)<<4) + ((k&31)>>1)] = by;
  }
  if((k&63)==0) tsumq[j*8 + (k>>6)] = (unsigned short)(int)wq;
  if(k==0){
    rscale[j] = rm * (1.0f/15.0f);
    rbar[j]   = rs - (rm * (1.0f/15.0f)) * qs;
  }
}

// ---------------- forward recurrence ----------------
// 64 blocks (1/batch), 512 threads = 8 waves. Round-11 skeleton (ONE barrier/step,
// ping-pong alpha/stats planes, stale-S normalizer, wave-local finalize) with the
// Tr row moved from LDS into REGISTERS: full 512-k u4 row = 256 B = 64 dwords,
// pinned via inline asm (round 7 proved 64 pinned dwords fit the 512-thread
// allocator budget: VGPR 116, no spill). This deletes round 11's 128 KB/step LDS
// stream (its 1536-cyc floor). alpha reads are wave-uniform b128 broadcasts
// (conflict-free, ~200 cyc/step). tell: VGPR ~100-120 = resident; <=64 = spilled.
__global__ __launch_bounds__(512)
void k_fwd(const int* __restrict__ x, const int* __restrict__ Tl,
           const unsigned short* __restrict__ emTu,
           const float* __restrict__ P, const float* __restrict__ pric,
           const float* __restrict__ rscaleG, const float* __restrict__ rbarG,
           const unsigned short* __restrict__ tsumqG,
           const uint4* __restrict__ TQd4,
           float* __restrict__ out){
  extern __shared__ char smem[];
  uint4*         apl4  = (uint4*)smem;                         // [2][16] uint4 = 512 B
  unsigned char* aplB  = (unsigned char*)smem;
  float*         sigS  = (float*)(smem + 512);                 // [2][8]
  float*         sumS  = (float*)(smem + 576);                 // [2][8]
  float*         aqS   = (float*)(smem + 640);                 // [2][8]
  float*         rawS  = (float*)(smem + 704);                 // [8]
  int*           xls   = (int*)(smem + 768);                   // 2048
  float*         rscL  = (float*)(smem + 2816);                // 2048
  float*         rbarL = (float*)(smem + 4864);                // 2048
  unsigned short* tsumL= (unsigned short*)(smem + 6912);       // 8192
  // total 15104 B

  const int t = threadIdx.x, b = blockIdx.x, w = t>>6, L = t&63;
  const int j = t;

  // ---- stage: Tr row into registers (16 uint4 = 64 dwords), tables into LDS ----
  unsigned int trq[64];
  #pragma unroll
  for(int q=0;q<16;q++) ((uint4*)trq)[q] = TQd4[j*16 + q];
  #pragma unroll
  for(int r=0;r<64;r++) asm volatile("" : "+v"(trq[r]));

  xls[t]   = x[b*HT + t];
  rscL[t]  = rscaleG[t];
  rbarL[t] = rbarG[t];
  for(int d=t; d<2048; d+=512) ((unsigned int*)tsumL)[d] = ((const unsigned int*)tsumqG)[d];
  int Tb = Tl[b];
  __syncthreads();

  // ---- init (t = 0) ----
  int m = xls[0];
  float e0 = bf2f((unsigned)emTu[(size_t)m*HN + j]);
  float nvr = e0 * P[j];
  {
    float s = wsum(nvr);
    if(L==0) rawS[w] = s;
  }
  __syncthreads();
  float4 q0 = ((float4*)rawS)[0], q1 = ((float4*)rawS)[1];
  float S0 = ((q0.x+q0.y)+(q0.z+q0.w))+((q1.x+q1.y)+(q1.z+q1.w));
  float c_acc = pric[0] + __logf(S0);
  float nvd = nvr * rcpf(S0);
  // quantize + stats into buffer 1 (read at tt=1)
  {
    float Mw = fmaxf(wmax(nvd), 1e-30f);
    float sig = Mw * (1.0f/15.0f);
    int aq = __float2int_rn(nvd * (15.0f * rcpf(Mw)));
    float Sw = wsum(nvd);
#if ENC_BIASED
    float AqSw = wsum((float)aq);
#endif
    int aqn = __shfl_xor(aq, 1, 64);
    if((j&1)==0){
#if ENC_BIASED
      aplB[256 + (j>>1)] = (unsigned char)(((aq-8)&0xF) | (((aqn-8)&0xF)<<4));
#else
      aplB[256 + (j>>1)] = (unsigned char)((aq&0xF) | ((aqn&0xF)<<4));
#endif
    }
    if(L==0){
      sigS[8+w] = sig; sumS[8+w] = Sw;
#if ENC_BIASED
      aqS[8+w] = AqSw;
#endif
    }
  }
  int mn = xls[(Tb>1)?1:0];
  float eC = bf2f((unsigned)emTu[(size_t)mn*HN + j]);
  const float rsc = rscL[j], rbr = rbarL[j];

  for(int tt=1; tt<Tb; tt++){
    __syncthreads();                      // the ONE barrier per step
    const int rb = (tt & 1), wb = rb ^ 1;

    // [a] full-row dot: 16 alpha chunks (wave-uniform b128 broadcast) vs register Tr
    int acc[8];
    #pragma unroll
    for(int i=0;i<8;i++) acc[i] = 0;
    const uint4* aplR = apl4 + 16*rb;
    #pragma unroll
    for(int c=0;c<16;c++){
      uint4 A = aplR[c];
      int wi = c>>1;
      acc[wi] = dot8q(trq[4*c+0], A.x, acc[wi]);
      acc[wi] = dot8q(trq[4*c+1], A.y, acc[wi]);
      acc[wi] = dot8q(trq[4*c+2], A.z, acc[wi]);
      acc[wi] = dot8q(trq[4*c+3], A.w, acc[wi]);
    }

    // [b] previous-step stats (uniform reads)
    float4 g0 = ((float4*)(sumS + 8*rb))[0], g1 = ((float4*)(sumS + 8*rb))[1];
    float Sp = ((g0.x+g0.y)+(g0.z+g0.w))+((g1.x+g1.y)+(g1.z+g1.w));
    if(tt > 1) c_acc += __logf(Sp);
    float d_inv = rcpf(Sp);
    float abar  = Sp * (1.0f/512.0f);
    float4 s0 = ((float4*)(sigS + 8*rb))[0], s1 = ((float4*)(sigS + 8*rb))[1];
    float sg[8] = {s0.x,s0.y,s0.z,s0.w,s1.x,s1.y,s1.z,s1.w};

    // [c] combine with per-slice alpha scales (+ sdot bias correction)
    float Af = 0.f;
#if ENC_BIASED
    {
      float4 a0 = ((float4*)(aqS + 8*rb))[0], a1 = ((float4*)(aqS + 8*rb))[1];
      float av[8] = {a0.x,a0.y,a0.z,a0.w,a1.x,a1.y,a1.z,a1.w};
      uint4 tq = ((const uint4*)tsumL)[j];
      int ts[8] = {(int)(tq.x&0xffff),(int)(tq.x>>16),(int)(tq.y&0xffff),(int)(tq.y>>16),
                   (int)(tq.z&0xffff),(int)(tq.z>>16),(int)(tq.w&0xffff),(int)(tq.w>>16)};
      #pragma unroll
      for(int i=0;i<8;i++)
        Af += sg[i] * (float)(acc[i] + 8*(ts[i] + (int)av[i]) - 4096);
    }
#else
    #pragma unroll
    for(int i=0;i<8;i++) Af += sg[i] * (float)acc[i];
#endif
    float D = rsc * Af + abar * rbr;
    nvd = fmaxf(D * eC * d_inv, 0.0f);

    // prefetch next emission
    int tn = (tt+1 < HT)? tt+1 : HT-1;
    mn = xls[tn];
    float eN = bf2f((unsigned)emTu[(size_t)mn*HN + j]);

    // [e] wave-local finalize: quantize vs wave max, write plane wb
    float Mw = fmaxf(wmax(nvd), 1e-30f);
    float sig = Mw * (1.0f/15.0f);
    int aq = __float2int_rn(nvd * (15.0f * rcpf(Mw)));
    float Sw = wsum(nvd);
#if ENC_BIASED
    float AqSw = wsum((float)aq);
#endif
    int aqn = __shfl_xor(aq, 1, 64);
    if((j&1)==0){
#if ENC_BIASED
      aplB[256*wb + (j>>1)] = (unsigned char)(((aq-8)&0xF) | (((aqn-8)&0xF)<<4));
#else
      aplB[256*wb + (j>>1)] = (unsigned char)((aq&0xF) | ((aqn&0xF)<<4));
#endif
    }
    if(L==0){
      sigS[8*wb+w] = sig; sumS[8*wb+w] = Sw;
#if ENC_BIASED
      aqS[8*wb+w] = AqSw;
#endif
    }
    eC = eN;
  }

  // ---- flush last step's S ----
  __syncthreads();
  {
    const int fb = (Tb & 1);
    float4 g0 = ((float4*)(sumS + 8*fb))[0], g1 = ((float4*)(sumS + 8*fb))[1];
    float Sf = ((g0.x+g0.y)+(g0.z+g0.w))+((g1.x+g1.y)+(g1.z+g1.w));
    if(t==0) out[b] = c_acc + __logf(Sf);
  }
}

extern "C" void kernel_launch(void* const* d_in, const int* in_sizes, int n_in,
                              void* d_out, int out_size, void* d_ws, size_t ws_size,
                              hipStream_t stream){
  const int*   x   = (const int*)d_in[0];
  const int*   T   = (const int*)d_in[1];
  const float* em  = (const float*)d_in[2];
  const float* tr  = (const float*)d_in[3];
  const float* pri = (const float*)d_in[4];
  float* out = (float*)d_out;

  char* ws = (char*)d_ws;
  float* em_lse = (float*)ws;                                   // 2 KiB
  float* P      = (float*)(ws + 2048);                          // 2 KiB
  float* pric   = (float*)(ws + 4096);                          // 16 B
  float* cmax   = (float*)(ws + 8192);                          // 2 KiB
  float* csum   = (float*)(ws + 10240);                         // 2 KiB
  float* rscale = (float*)(ws + 12288);                         // 2 KiB
  float* rbar   = (float*)(ws + 14336);                         // 2 KiB
  unsigned short* tsumq = (unsigned short*)(ws + 16384);        // 8 KiB
  unsigned short* emT = (unsigned short*)(ws + 24576);          // 4 MiB
  unsigned char*  TQ4 = (unsigned char*)(ws + 24576 + (size_t)HM*HN*2);  // 128 KiB

  k_em_lse<<<HN, 512, 0, stream>>>(em, em_lse);
  k_pri   <<<1,  512, 0, stream>>>(pri, P, pric);
  k_trcol <<<HN, 512, 0, stream>>>(tr, cmax, csum);
  k_trrow <<<HN, 512, 0, stream>>>(tr, cmax, csum, TQ4, rscale, rbar, tsumq);
  k_em_tab<<<dim3(HM/64, HN/64), 256, 0, stream>>>(em, em_lse, emT);

  const int lds_bytes = 15104;
  (void)hipFuncSetAttribute((const void*)k_fwd, hipFuncAttributeMaxDynamicSharedMemorySize, lds_bytes);
  k_fwd<<<HB, 512, lds_bytes, stream>>>(x, T, emT, P, pric, rscale, rbar, tsumq,
                                        (const uint4*)TQ4, out);
}